// Round 1
// baseline (27554.718 us; speedup 1.0000x reference)
//
#include <hip/hip_runtime.h>

// ---------------- problem constants ----------------
static constexpr int B  = 4;
static constexpr int N0 = 2048;
static constexpr int LF = 8;
static constexpr int M1 = 1024, M2 = 512, M3 = 256;
static constexpr int O1 = 64, O2 = 128, O3 = 256;
static constexpr int NS1 = 12, NS2 = 8, NS3 = 4, NSQ = 4;
static constexpr int C1 = 67, C2 = 195, C3 = 387;

// Exact float32 squared distance in numpy's op order ((dx^2+dy^2)+dz^2),
// with _rn intrinsics to forbid FMA contraction (discrete decisions depend on it).
__device__ __forceinline__ float sq3(float ax, float ay, float az,
                                     float bx, float by, float bz) {
  float dx = __fsub_rn(ax, bx), dy = __fsub_rn(ay, by), dz = __fsub_rn(az, bz);
  return __fadd_rn(__fadd_rn(__fmul_rn(dx, dx), __fmul_rn(dy, dy)),
                   __fmul_rn(dz, dz));
}

// ---------------- furthest point sampling ----------------
// One block (256 thr) per batch; emits gathered coords directly.
// Tie-break: jnp.argmax = first max occurrence => prefer smaller index on equal.
__global__ __launch_bounds__(256) void fps_kernel(const float* __restrict__ pts,
                                                  long bstride, int N, int npoint,
                                                  float* __restrict__ out) {
  const int b = blockIdx.x;
  const float* p = pts + (long)b * bstride;
  __shared__ float px[2048], py[2048], pz[2048], dist[2048];
  __shared__ float wv[4];
  __shared__ int wi[4];
  __shared__ int s_last;
  const int tid = threadIdx.x;
  for (int j = tid; j < N; j += 256) {
    px[j] = p[3 * j + 0];
    py[j] = p[3 * j + 1];
    pz[j] = p[3 * j + 2];
    dist[j] = 1e10f;
  }
  __syncthreads();
  int last = 0;
  for (int i = 0; i < npoint; ++i) {
    const float lx = px[last], ly = py[last], lz = pz[last];
    if (tid == 0) {
      float* o = out + ((long)b * npoint + i) * 3;
      o[0] = lx; o[1] = ly; o[2] = lz;
    }
    float bv = -1.0f;
    int bi = 0x7fffffff;
    for (int j = tid; j < N; j += 256) {
      float d = sq3(px[j], py[j], pz[j], lx, ly, lz);
      float dm = fminf(dist[j], d);
      dist[j] = dm;
      if (dm > bv) { bv = dm; bi = j; }
    }
#pragma unroll
    for (int off = 32; off; off >>= 1) {
      float ov = __shfl_down(bv, off, 64);
      int oi = __shfl_down(bi, off, 64);
      if (ov > bv || (ov == bv && oi < bi)) { bv = ov; bi = oi; }
    }
    if ((tid & 63) == 0) { wv[tid >> 6] = bv; wi[tid >> 6] = bi; }
    __syncthreads();
    if (tid == 0) {
      float v = wv[0]; int ix = wi[0];
#pragma unroll
      for (int w2 = 1; w2 < 4; ++w2)
        if (wv[w2] > v || (wv[w2] == v && wi[w2] < ix)) { v = wv[w2]; ix = wi[w2]; }
      s_last = ix;
    }
    __syncthreads();
    last = s_last;
  }
}

// ---------------- ball query ----------------
// First ns in-range indices in ascending order; pad with first; 0 if none.
__global__ __launch_bounds__(256) void bq_kernel(const float* __restrict__ nxyz,
                                                 const float* __restrict__ sxyz,
                                                 float r2, int ns, int M, int Ns,
                                                 int* __restrict__ idx, int total) {
  int t = blockIdx.x * 256 + threadIdx.x;
  if (t >= total) return;
  int b = t / M;
  const float* q = nxyz + (long)t * 3;
  const float qx = q[0], qy = q[1], qz = q[2];
  const float* s = sxyz + (long)b * Ns * 3;
  int* o = idx + (long)t * ns;
  int cnt = 0;
  for (int j = 0; j < Ns; ++j) {
    float d2 = sq3(qx, qy, qz, s[3 * j], s[3 * j + 1], s[3 * j + 2]);
    if (d2 < r2) {
      o[cnt++] = j;
      if (cnt == ns) break;
    }
  }
  int fill = (cnt > 0) ? o[0] : 0;
  for (int k = cnt; k < ns; ++k) o[k] = fill;
}

// ---------------- point-rnn cell: S_out = max_s W @ [S2g; X1; disp] ----------------
// One block per (b,m), blockDim == O (one thread per output channel).
__global__ void cell_kernel(const float* __restrict__ P1, const float* __restrict__ X1,
                            const float* __restrict__ P2, const float* __restrict__ S2,
                            const int* __restrict__ idx, const float* __restrict__ W,
                            float* __restrict__ Sout, int M, int ns, int Cin, int O) {
  const int C = O + Cin + 3;
  const int bm = blockIdx.x;
  const int b = bm / M, m = bm - b * M;
  extern __shared__ float corr[];  // ns*C
  const int* id = idx + (long)bm * ns;
  const float p1x = P1[bm * 3 + 0], p1y = P1[bm * 3 + 1], p1z = P1[bm * 3 + 2];
  for (int e = threadIdx.x; e < ns * C; e += blockDim.x) {
    int s = e / C, c = e - s * C;
    int j = id[s];
    float v;
    if (c < O) {
      v = S2[((long)b * O + c) * M + j];
    } else if (c < O + Cin) {
      v = X1[((long)b * Cin + (c - O)) * M + m];
    } else {
      int d = c - O - Cin;
      float pj = P2[((long)b * M + j) * 3 + d];
      float pm = (d == 0) ? p1x : ((d == 1) ? p1y : p1z);
      v = __fsub_rn(pj, pm);
    }
    corr[e] = v;
  }
  __syncthreads();
  const int o = threadIdx.x;
  const float* w = W + (long)o * C;
  float best = -3.0e38f;
  for (int s = 0; s < ns; ++s) {
    const float* cs = corr + s * C;
    float acc = 0.f;
    for (int c = 0; c < C; ++c) acc = fmaf(w[c], cs[c], acc);
    best = fmaxf(best, acc);
  }
  Sout[((long)b * O + o) * M + m] = best;
}

// ---------------- grouped feature max ----------------
__global__ __launch_bounds__(256) void gmax_kernel(const float* __restrict__ feat,
                                                   const int* __restrict__ idx,
                                                   float* __restrict__ out, int Cc,
                                                   int M, int Ms, int ns, int total) {
  int t = blockIdx.x * 256 + threadIdx.x;
  if (t >= total) return;
  int m = t % M;
  int bc = t / M;
  int b = bc / Cc;
  const int* id = idx + ((long)b * M + m) * ns;
  const float* f = feat + (long)bc * Ms;
  float best = -3.0e38f;
  for (int s = 0; s < ns; ++s) best = fmaxf(best, f[id[s]]);
  out[t] = best;
}

// ---------------- 3-NN + inverse-distance weights ----------------
// Strict '<' insertion matches lax.top_k tie semantics (lower index first).
__global__ __launch_bounds__(256) void knn3_kernel(const float* __restrict__ unk,
                                                   long ubstride, int Mu,
                                                   const float* __restrict__ kn, int Mk,
                                                   int* __restrict__ oi,
                                                   float* __restrict__ ow, int total) {
  int t = blockIdx.x * 256 + threadIdx.x;
  if (t >= total) return;
  int b = t / Mu, m = t - b * Mu;
  const float* q = unk + (long)b * ubstride + (long)m * 3;
  const float qx = q[0], qy = q[1], qz = q[2];
  const float* s = kn + (long)b * Mk * 3;
  float d0 = 3e38f, d1 = 3e38f, d2v = 3e38f;
  int i0 = 0, i1 = 0, i2 = 0;
  for (int j = 0; j < Mk; ++j) {
    float dd = sq3(qx, qy, qz, s[3 * j], s[3 * j + 1], s[3 * j + 2]);
    if (dd < d0) {
      d2v = d1; i2 = i1; d1 = d0; i1 = i0; d0 = dd; i0 = j;
    } else if (dd < d1) {
      d2v = d1; i2 = i1; d1 = dd; i1 = j;
    } else if (dd < d2v) {
      d2v = dd; i2 = j;
    }
  }
  float r0 = 1.0f / __fadd_rn(d0, 1e-8f);
  float r1 = 1.0f / __fadd_rn(d1, 1e-8f);
  float r2 = 1.0f / __fadd_rn(d2v, 1e-8f);
  float sum = __fadd_rn(__fadd_rn(r0, r1), r2);
  ow[t * 3 + 0] = r0 / sum;
  ow[t * 3 + 1] = r1 / sum;
  ow[t * 3 + 2] = r2 / sum;
  oi[t * 3 + 0] = i0;
  oi[t * 3 + 1] = i1;
  oi[t * 3 + 2] = i2;
}

// ---------------- weighted 3-gather (interp) into concat region ----------------
__global__ __launch_bounds__(256) void interp_kernel(const float* __restrict__ f,
                                                     const int* __restrict__ ii,
                                                     const float* __restrict__ iw,
                                                     float* __restrict__ out, int Cc,
                                                     int Coff, int Ctot, int Ms, int Md,
                                                     int total) {
  int t = blockIdx.x * 256 + threadIdx.x;
  if (t >= total) return;
  int m = t % Md;
  int bc = t / Md;
  int c = bc % Cc;
  int b = bc / Cc;
  const int* id = ii + ((long)b * Md + m) * 3;
  const float* w = iw + ((long)b * Md + m) * 3;
  const float* fb = f + ((long)b * Cc + c) * Ms;
  float v = __fadd_rn(__fadd_rn(__fmul_rn(fb[id[0]], w[0]), __fmul_rn(fb[id[1]], w[1])),
                      __fmul_rn(fb[id[2]], w[2]));
  out[((long)b * Ctot + Coff + c) * Md + m] = v;
}

__global__ __launch_bounds__(256) void copyrows_kernel(const float* __restrict__ f,
                                                       float* __restrict__ out, int Cc,
                                                       int Coff, int Ctot, int M,
                                                       int total) {
  int t = blockIdx.x * 256 + threadIdx.x;
  if (t >= total) return;
  int m = t % M;
  int bc = t / M;
  int c = bc % Cc;
  int b = bc / Cc;
  out[((long)b * Ctot + Coff + c) * M + m] = f[t];
}

__global__ __launch_bounds__(256) void copyframe_kernel(const float* __restrict__ xyzs,
                                                        float* __restrict__ frame,
                                                        int total) {
  int t = blockIdx.x * 256 + threadIdx.x;
  if (t >= total) return;
  int b = t / (N0 * 3);
  int rr = t - b * (N0 * 3);
  frame[t] = xyzs[((long)b * LF + (LF / 2 - 1)) * (N0 * 3) + rr];
}

// ---------------- fused interp-to-l1 + 2-layer MLP + frame update ----------------
__global__ __launch_bounds__(64) void mlp_kernel(const float* __restrict__ l2,
                                                 const int* __restrict__ ii,
                                                 const float* __restrict__ iw,
                                                 const float* __restrict__ W1,
                                                 const float* __restrict__ b1,
                                                 const float* __restrict__ W2,
                                                 const float* __restrict__ b2,
                                                 float* __restrict__ frame,
                                                 float* __restrict__ out, int td) {
  const int bn = blockIdx.x;
  const int b = bn / N0, n = bn - b * N0;
  __shared__ float col[448];
  __shared__ float h[64];
  const int* id = ii + (long)bn * 3;
  const float* w = iw + (long)bn * 3;
  const float w0 = w[0], w1 = w[1], w2v = w[2];
  const int i0 = id[0], i1 = id[1], i2 = id[2];
  const float* l2b = l2 + (long)b * 448 * M1;
  for (int c = threadIdx.x; c < 448; c += 64) {
    const float* r = l2b + (long)c * M1;
    col[c] = __fadd_rn(__fadd_rn(__fmul_rn(r[i0], w0), __fmul_rn(r[i1], w1)),
                       __fmul_rn(r[i2], w2v));
  }
  __syncthreads();
  const int o = threadIdx.x;
  const float* wr = W1 + (long)o * 448;
  float acc = b1[o];
  for (int c = 0; c < 448; ++c) acc = fmaf(wr[c], col[c], acc);
  h[o] = fmaxf(acc, 0.0f);
  __syncthreads();
  if (o < 3) {
    const float* w2r = W2 + o * 64;
    float acc2 = b2[o];
    for (int c = 0; c < 64; ++c) acc2 = fmaf(w2r[c], h[c], acc2);
    float nf = frame[(long)bn * 3 + o] + acc2;
    frame[(long)bn * 3 + o] = nf;
    out[(((long)b * 4 + td) * N0 + n) * 3 + o] = nf;
  }
}

extern "C" void kernel_launch(void* const* d_in, const int* in_sizes, int n_in,
                              void* d_out, int out_size, void* d_ws, size_t ws_size,
                              hipStream_t stream) {
  const float* xyzs = (const float*)d_in[0];
  const float* enw[3] = {(const float*)d_in[1], (const float*)d_in[2], (const float*)d_in[3]};
  const float* dew[3] = {(const float*)d_in[4], (const float*)d_in[5], (const float*)d_in[6]};
  const float* mw1 = (const float*)d_in[7];
  const float* mb1 = (const float*)d_in[8];
  const float* mw2 = (const float*)d_in[9];
  const float* mb2 = (const float*)d_in[10];
  float* out = (float*)d_out;

  float* ws = (float*)d_ws;
  size_t off = 0;
  auto alloc = [&](size_t nn) { float* p = ws + off; off += nn; return p; };
  float* frame = alloc((size_t)B * N0 * 3);
  float* xyz1b[2] = {alloc((size_t)B * M1 * 3), alloc((size_t)B * M1 * 3)};
  float* xyz2b[2] = {alloc((size_t)B * M2 * 3), alloc((size_t)B * M2 * 3)};
  float* xyz3b[2] = {alloc((size_t)B * M3 * 3), alloc((size_t)B * M3 * 3)};
  float* S1bf[2] = {alloc((size_t)B * O1 * M1), alloc((size_t)B * O1 * M1)};
  float* S2bf[2] = {alloc((size_t)B * O2 * M2), alloc((size_t)B * O2 * M2)};
  float* S3bf[2] = {alloc((size_t)B * O3 * M3), alloc((size_t)B * O3 * M3)};
  float* feat2 = alloc((size_t)B * O1 * M2);
  float* feat3 = alloc((size_t)B * O2 * M3);
  float* l3 = alloc((size_t)B * 384 * M2);
  float* l2 = alloc((size_t)B * 448 * M1);
  float* iw = alloc((size_t)B * N0 * 3);
  int* ii = (int*)alloc((size_t)B * N0 * 3);
  int* idxc = (int*)alloc((size_t)B * M1 * NS1);
  int* idxq = (int*)alloc((size_t)B * M2 * NSQ);

  // zero-init the t=0 "previous state" buffers (ping index 1)
  hipMemsetAsync(xyz1b[1], 0, (size_t)B * M1 * 3 * 4, stream);
  hipMemsetAsync(xyz2b[1], 0, (size_t)B * M2 * 3 * 4, stream);
  hipMemsetAsync(xyz3b[1], 0, (size_t)B * M3 * 3 * 4, stream);
  hipMemsetAsync(S1bf[1], 0, (size_t)B * O1 * M1 * 4, stream);
  hipMemsetAsync(S2bf[1], 0, (size_t)B * O2 * M2 * 4, stream);
  hipMemsetAsync(S3bf[1], 0, (size_t)B * O3 * M3 * 4, stream);

  double r;
  r = 4.0 + 1e-6;         const float r2c1 = (float)(r * r);
  r = 2.0 * 4.0 / 4.0 + 1e-6; const float r2q2 = (float)(r * r);
  r = 2.0 * 4.0 + 1e-6;   const float r2c2 = (float)(r * r);
  r = 4.0 * 4.0 / 4.0 + 1e-6; const float r2q3 = (float)(r * r);
  r = 3.0 * 4.0 + 1e-6;   const float r2c3 = (float)(r * r);

  auto grid = [](int total) { return dim3((unsigned)((total + 255) / 256)); };

  int cur = 0;
  for (int t = 0; t < LF; ++t) {
    const bool enc = t < LF / 2;
    const float* W1 = enc ? enw[0] : dew[0];
    const float* W2 = enc ? enw[1] : dew[1];
    const float* W3 = enc ? enw[2] : dew[2];
    const float* fp;
    long fstr;
    if (enc) {
      fp = xyzs + (long)t * N0 * 3;
      fstr = (long)LF * N0 * 3;
    } else {
      if (t == LF / 2)
        copyframe_kernel<<<grid(B * N0 * 3), 256, 0, stream>>>(xyzs, frame, B * N0 * 3);
      fp = frame;
      fstr = (long)N0 * 3;
    }
    const int prev = 1 - cur;

    // ---- level 1 ----
    fps_kernel<<<B, 256, 0, stream>>>(fp, fstr, N0, M1, xyz1b[cur]);
    bq_kernel<<<grid(B * M1), 256, 0, stream>>>(xyz1b[cur], xyz1b[prev], r2c1, NS1, M1, M1,
                                                idxc, B * M1);
    cell_kernel<<<B * M1, O1, NS1 * C1 * 4, stream>>>(xyz1b[cur], nullptr, xyz1b[prev],
                                                      S1bf[prev], idxc, W1, S1bf[cur], M1,
                                                      NS1, 0, O1);
    // ---- level 2 ----
    fps_kernel<<<B, 256, 0, stream>>>(xyz1b[cur], (long)M1 * 3, M1, M2, xyz2b[cur]);
    bq_kernel<<<grid(B * M2), 256, 0, stream>>>(xyz2b[cur], xyz1b[cur], r2q2, NSQ, M2, M1,
                                                idxq, B * M2);
    gmax_kernel<<<grid(B * O1 * M2), 256, 0, stream>>>(S1bf[cur], idxq, feat2, O1, M2, M1,
                                                       NSQ, B * O1 * M2);
    bq_kernel<<<grid(B * M2), 256, 0, stream>>>(xyz2b[cur], xyz2b[prev], r2c2, NS2, M2, M2,
                                                idxc, B * M2);
    cell_kernel<<<B * M2, O2, NS2 * C2 * 4, stream>>>(xyz2b[cur], feat2, xyz2b[prev],
                                                      S2bf[prev], idxc, W2, S2bf[cur], M2,
                                                      NS2, O1, O2);
    // ---- level 3 ----
    fps_kernel<<<B, 256, 0, stream>>>(xyz2b[cur], (long)M2 * 3, M2, M3, xyz3b[cur]);
    bq_kernel<<<grid(B * M3), 256, 0, stream>>>(xyz3b[cur], xyz2b[cur], r2q3, NSQ, M3, M2,
                                                idxq, B * M3);
    gmax_kernel<<<grid(B * O2 * M3), 256, 0, stream>>>(S2bf[cur], idxq, feat3, O2, M3, M2,
                                                       NSQ, B * O2 * M3);
    bq_kernel<<<grid(B * M3), 256, 0, stream>>>(xyz3b[cur], xyz3b[prev], r2c3, NS3, M3, M3,
                                                idxc, B * M3);
    cell_kernel<<<B * M3, O3, NS3 * C3 * 4, stream>>>(xyz3b[cur], feat3, xyz3b[prev],
                                                      S3bf[prev], idxc, W3, S3bf[cur], M3,
                                                      NS3, O2, O3);

    if (!enc) {
      const int td = t - LF / 2;
      // l3 = concat([interp(p2<-p3, f3), f2])
      knn3_kernel<<<grid(B * M2), 256, 0, stream>>>(xyz2b[cur], (long)M2 * 3, M2,
                                                    xyz3b[cur], M3, ii, iw, B * M2);
      interp_kernel<<<grid(B * O3 * M2), 256, 0, stream>>>(S3bf[cur], ii, iw, l3, O3, 0,
                                                           384, M3, M2, B * O3 * M2);
      copyrows_kernel<<<grid(B * O2 * M2), 256, 0, stream>>>(S2bf[cur], l3, O2, O3, 384,
                                                             M2, B * O2 * M2);
      // l2 = concat([interp(p1<-p2, l3), f1])
      knn3_kernel<<<grid(B * M1), 256, 0, stream>>>(xyz1b[cur], (long)M1 * 3, M1,
                                                    xyz2b[cur], M2, ii, iw, B * M1);
      interp_kernel<<<grid(B * 384 * M1), 256, 0, stream>>>(l3, ii, iw, l2, 384, 0, 448,
                                                            M2, M1, B * 384 * M1);
      copyrows_kernel<<<grid(B * O1 * M1), 256, 0, stream>>>(S1bf[cur], l2, O1, 384, 448,
                                                             M1, B * O1 * M1);
      // l1 = interp(frame<-p1, l2) fused into MLP; frame += motion; emit pred
      knn3_kernel<<<grid(B * N0), 256, 0, stream>>>(frame, (long)N0 * 3, N0, xyz1b[cur],
                                                    M1, ii, iw, B * N0);
      mlp_kernel<<<B * N0, 64, 0, stream>>>(l2, ii, iw, mw1, mb1, mw2, mb2, frame, out, td);
    }
    cur = prev;
  }
  (void)in_sizes; (void)n_in; (void)out_size; (void)ws_size;
}

// Round 2
// 21292.921 us; speedup vs baseline: 1.2941x; 1.2941x over previous
//
#include <hip/hip_runtime.h>

// ---------------- problem constants ----------------
static constexpr int B  = 4;
static constexpr int N0 = 2048;
static constexpr int LF = 8;
static constexpr int M1 = 1024, M2 = 512, M3 = 256;
static constexpr int O1 = 64, O2 = 128, O3 = 256;
static constexpr int NS1 = 12, NS2 = 8, NS3 = 4, NSQ = 4;
static constexpr int C1 = 67, C2 = 195, C3 = 387;

// Exact float32 squared distance in numpy's op order ((dx^2+dy^2)+dz^2),
// with _rn intrinsics to forbid FMA contraction (discrete decisions depend on it).
__device__ __forceinline__ float sq3(float ax, float ay, float az,
                                     float bx, float by, float bz) {
  float dx = __fsub_rn(ax, bx), dy = __fsub_rn(ay, by), dz = __fsub_rn(az, bz);
  return __fadd_rn(__fadd_rn(__fmul_rn(dx, dx), __fmul_rn(dy, dy)),
                   __fmul_rn(dz, dz));
}

// ---------------- furthest point sampling (latency-optimized) ----------------
// One block per batch. Blocked point ownership (thread t owns t*K..t*K+K-1),
// dist in registers, packed-u64 (val, 0x7FFFFFFF-j) argmax => max value with
// first-occurrence (min index) tie-break, matching jnp.argmax exactly.
// One barrier per iteration (wbest parity double-buffered: a wave cannot
// overwrite parity p before all waves pass the next barrier, which orders
// after all reads of parity p).
template <int N, int BLK>
__global__ __launch_bounds__(BLK) void fps_fast(const float* __restrict__ pts,
                                                long bstride, int npoint,
                                                float* __restrict__ out) {
  constexpr int K = N / BLK;
  constexpr int NW = BLK / 64;
  const int b = blockIdx.x;
  const float* p = pts + (long)b * bstride;
  const int tid = threadIdx.x;
  const int lane = tid & 63;
  const int wid = tid >> 6;
  __shared__ float spx[N], spy[N], spz[N];
  __shared__ unsigned long long wbest[2][NW];
  float ppx[K], ppy[K], ppz[K], dist[K];
#pragma unroll
  for (int k = 0; k < K; ++k) {
    const int j = tid * K + k;
    const float x = p[3 * j], y = p[3 * j + 1], z = p[3 * j + 2];
    ppx[k] = x; ppy[k] = y; ppz[k] = z;
    spx[j] = x; spy[j] = y; spz[j] = z;
    dist[k] = 1e10f;
  }
  __syncthreads();
  float lx = spx[0], ly = spy[0], lz = spz[0];
  float* outb = out + (long)b * npoint * 3;
  for (int i = 0; i < npoint; ++i) {
    if (tid == 0) {
      outb[3 * i + 0] = lx; outb[3 * i + 1] = ly; outb[3 * i + 2] = lz;
    }
    unsigned long long key = 0ull;
#pragma unroll
    for (int k = 0; k < K; ++k) {
      const float d = sq3(ppx[k], ppy[k], ppz[k], lx, ly, lz);
      const float dm = fminf(dist[k], d);
      dist[k] = dm;
      const unsigned long long kk =
          ((unsigned long long)__float_as_uint(dm) << 32) |
          (unsigned)(0x7FFFFFFF - (tid * K + k));
      key = (kk > key) ? kk : key;
    }
#pragma unroll
    for (int off = 1; off < 64; off <<= 1) {
      const unsigned long long o = __shfl_xor(key, off, 64);
      key = (o > key) ? o : key;
    }
    if (lane == 0) wbest[i & 1][wid] = key;
    __syncthreads();
    unsigned long long gk = wbest[i & 1][0];
#pragma unroll
    for (int w = 1; w < NW; ++w) {
      const unsigned long long o = wbest[i & 1][w];
      gk = (o > gk) ? o : gk;
    }
    const int gidx = 0x7FFFFFFF - (int)(gk & 0xFFFFFFFFu);
    lx = spx[gidx]; ly = spy[gidx]; lz = spz[gidx];
  }
}

// ---------------- ball query ----------------
// First ns in-range indices in ascending order; pad with first; 0 if none.
__global__ __launch_bounds__(256) void bq_kernel(const float* __restrict__ nxyz,
                                                 const float* __restrict__ sxyz,
                                                 float r2, int ns, int M, int Ns,
                                                 int* __restrict__ idx, int total) {
  int t = blockIdx.x * 256 + threadIdx.x;
  if (t >= total) return;
  int b = t / M;
  const float* q = nxyz + (long)t * 3;
  const float qx = q[0], qy = q[1], qz = q[2];
  const float* s = sxyz + (long)b * Ns * 3;
  int* o = idx + (long)t * ns;
  int cnt = 0;
  for (int j = 0; j < Ns; ++j) {
    float d2 = sq3(qx, qy, qz, s[3 * j], s[3 * j + 1], s[3 * j + 2]);
    if (d2 < r2) {
      o[cnt++] = j;
      if (cnt == ns) break;
    }
  }
  int fill = (cnt > 0) ? o[0] : 0;
  for (int k = cnt; k < ns; ++k) o[k] = fill;
}

// ---------------- point-rnn cell: S_out = max_s W @ [S2g; X1; disp] ----------------
// One block per (b,m), blockDim == O (one thread per output channel).
__global__ void cell_kernel(const float* __restrict__ P1, const float* __restrict__ X1,
                            const float* __restrict__ P2, const float* __restrict__ S2,
                            const int* __restrict__ idx, const float* __restrict__ W,
                            float* __restrict__ Sout, int M, int ns, int Cin, int O) {
  const int C = O + Cin + 3;
  const int bm = blockIdx.x;
  const int b = bm / M, m = bm - b * M;
  extern __shared__ float corr[];  // ns*C
  const int* id = idx + (long)bm * ns;
  const float p1x = P1[bm * 3 + 0], p1y = P1[bm * 3 + 1], p1z = P1[bm * 3 + 2];
  for (int e = threadIdx.x; e < ns * C; e += blockDim.x) {
    int s = e / C, c = e - s * C;
    int j = id[s];
    float v;
    if (c < O) {
      v = S2[((long)b * O + c) * M + j];
    } else if (c < O + Cin) {
      v = X1[((long)b * Cin + (c - O)) * M + m];
    } else {
      int d = c - O - Cin;
      float pj = P2[((long)b * M + j) * 3 + d];
      float pm = (d == 0) ? p1x : ((d == 1) ? p1y : p1z);
      v = __fsub_rn(pj, pm);
    }
    corr[e] = v;
  }
  __syncthreads();
  const int o = threadIdx.x;
  const float* w = W + (long)o * C;
  float best = -3.0e38f;
  for (int s = 0; s < ns; ++s) {
    const float* cs = corr + s * C;
    float acc = 0.f;
    for (int c = 0; c < C; ++c) acc = fmaf(w[c], cs[c], acc);
    best = fmaxf(best, acc);
  }
  Sout[((long)b * O + o) * M + m] = best;
}

// ---------------- grouped feature max ----------------
__global__ __launch_bounds__(256) void gmax_kernel(const float* __restrict__ feat,
                                                   const int* __restrict__ idx,
                                                   float* __restrict__ out, int Cc,
                                                   int M, int Ms, int ns, int total) {
  int t = blockIdx.x * 256 + threadIdx.x;
  if (t >= total) return;
  int m = t % M;
  int bc = t / M;
  int b = bc / Cc;
  const int* id = idx + ((long)b * M + m) * ns;
  const float* f = feat + (long)bc * Ms;
  float best = -3.0e38f;
  for (int s = 0; s < ns; ++s) best = fmaxf(best, f[id[s]]);
  out[t] = best;
}

// ---------------- 3-NN + inverse-distance weights ----------------
// Strict '<' insertion matches lax.top_k tie semantics (lower index first).
__global__ __launch_bounds__(256) void knn3_kernel(const float* __restrict__ unk,
                                                   long ubstride, int Mu,
                                                   const float* __restrict__ kn, int Mk,
                                                   int* __restrict__ oi,
                                                   float* __restrict__ ow, int total) {
  int t = blockIdx.x * 256 + threadIdx.x;
  if (t >= total) return;
  int b = t / Mu, m = t - b * Mu;
  const float* q = unk + (long)b * ubstride + (long)m * 3;
  const float qx = q[0], qy = q[1], qz = q[2];
  const float* s = kn + (long)b * Mk * 3;
  float d0 = 3e38f, d1 = 3e38f, d2v = 3e38f;
  int i0 = 0, i1 = 0, i2 = 0;
  for (int j = 0; j < Mk; ++j) {
    float dd = sq3(qx, qy, qz, s[3 * j], s[3 * j + 1], s[3 * j + 2]);
    if (dd < d0) {
      d2v = d1; i2 = i1; d1 = d0; i1 = i0; d0 = dd; i0 = j;
    } else if (dd < d1) {
      d2v = d1; i2 = i1; d1 = dd; i1 = j;
    } else if (dd < d2v) {
      d2v = dd; i2 = j;
    }
  }
  float r0 = 1.0f / __fadd_rn(d0, 1e-8f);
  float r1 = 1.0f / __fadd_rn(d1, 1e-8f);
  float r2 = 1.0f / __fadd_rn(d2v, 1e-8f);
  float sum = __fadd_rn(__fadd_rn(r0, r1), r2);
  ow[t * 3 + 0] = r0 / sum;
  ow[t * 3 + 1] = r1 / sum;
  ow[t * 3 + 2] = r2 / sum;
  oi[t * 3 + 0] = i0;
  oi[t * 3 + 1] = i1;
  oi[t * 3 + 2] = i2;
}

// ---------------- weighted 3-gather (interp) into concat region ----------------
__global__ __launch_bounds__(256) void interp_kernel(const float* __restrict__ f,
                                                     const int* __restrict__ ii,
                                                     const float* __restrict__ iw,
                                                     float* __restrict__ out, int Cc,
                                                     int Coff, int Ctot, int Ms, int Md,
                                                     int total) {
  int t = blockIdx.x * 256 + threadIdx.x;
  if (t >= total) return;
  int m = t % Md;
  int bc = t / Md;
  int c = bc % Cc;
  int b = bc / Cc;
  const int* id = ii + ((long)b * Md + m) * 3;
  const float* w = iw + ((long)b * Md + m) * 3;
  const float* fb = f + ((long)b * Cc + c) * Ms;
  float v = __fadd_rn(__fadd_rn(__fmul_rn(fb[id[0]], w[0]), __fmul_rn(fb[id[1]], w[1])),
                      __fmul_rn(fb[id[2]], w[2]));
  out[((long)b * Ctot + Coff + c) * Md + m] = v;
}

__global__ __launch_bounds__(256) void copyrows_kernel(const float* __restrict__ f,
                                                       float* __restrict__ out, int Cc,
                                                       int Coff, int Ctot, int M,
                                                       int total) {
  int t = blockIdx.x * 256 + threadIdx.x;
  if (t >= total) return;
  int m = t % M;
  int bc = t / M;
  int c = bc % Cc;
  int b = bc / Cc;
  out[((long)b * Ctot + Coff + c) * M + m] = f[t];
}

__global__ __launch_bounds__(256) void copyframe_kernel(const float* __restrict__ xyzs,
                                                        float* __restrict__ frame,
                                                        int total) {
  int t = blockIdx.x * 256 + threadIdx.x;
  if (t >= total) return;
  int b = t / (N0 * 3);
  int rr = t - b * (N0 * 3);
  frame[t] = xyzs[((long)b * LF + (LF / 2 - 1)) * (N0 * 3) + rr];
}

// ---------------- fused interp-to-l1 + 2-layer MLP + frame update ----------------
__global__ __launch_bounds__(64) void mlp_kernel(const float* __restrict__ l2,
                                                 const int* __restrict__ ii,
                                                 const float* __restrict__ iw,
                                                 const float* __restrict__ W1,
                                                 const float* __restrict__ b1,
                                                 const float* __restrict__ W2,
                                                 const float* __restrict__ b2,
                                                 float* __restrict__ frame,
                                                 float* __restrict__ out, int td) {
  const int bn = blockIdx.x;
  const int b = bn / N0, n = bn - b * N0;
  __shared__ float col[448];
  __shared__ float h[64];
  const int* id = ii + (long)bn * 3;
  const float* w = iw + (long)bn * 3;
  const float w0 = w[0], w1 = w[1], w2v = w[2];
  const int i0 = id[0], i1 = id[1], i2 = id[2];
  const float* l2b = l2 + (long)b * 448 * M1;
  for (int c = threadIdx.x; c < 448; c += 64) {
    const float* r = l2b + (long)c * M1;
    col[c] = __fadd_rn(__fadd_rn(__fmul_rn(r[i0], w0), __fmul_rn(r[i1], w1)),
                       __fmul_rn(r[i2], w2v));
  }
  __syncthreads();
  const int o = threadIdx.x;
  const float* wr = W1 + (long)o * 448;
  float acc = b1[o];
  for (int c = 0; c < 448; ++c) acc = fmaf(wr[c], col[c], acc);
  h[o] = fmaxf(acc, 0.0f);
  __syncthreads();
  if (o < 3) {
    const float* w2r = W2 + o * 64;
    float acc2 = b2[o];
    for (int c = 0; c < 64; ++c) acc2 = fmaf(w2r[c], h[c], acc2);
    float nf = frame[(long)bn * 3 + o] + acc2;
    frame[(long)bn * 3 + o] = nf;
    out[(((long)b * 4 + td) * N0 + n) * 3 + o] = nf;
  }
}

extern "C" void kernel_launch(void* const* d_in, const int* in_sizes, int n_in,
                              void* d_out, int out_size, void* d_ws, size_t ws_size,
                              hipStream_t stream) {
  const float* xyzs = (const float*)d_in[0];
  const float* enw[3] = {(const float*)d_in[1], (const float*)d_in[2], (const float*)d_in[3]};
  const float* dew[3] = {(const float*)d_in[4], (const float*)d_in[5], (const float*)d_in[6]};
  const float* mw1 = (const float*)d_in[7];
  const float* mb1 = (const float*)d_in[8];
  const float* mw2 = (const float*)d_in[9];
  const float* mb2 = (const float*)d_in[10];
  float* out = (float*)d_out;

  float* ws = (float*)d_ws;
  size_t off = 0;
  auto alloc = [&](size_t nn) { float* p = ws + off; off += nn; return p; };
  float* frame = alloc((size_t)B * N0 * 3);
  float* xyz1b[2] = {alloc((size_t)B * M1 * 3), alloc((size_t)B * M1 * 3)};
  float* xyz2b[2] = {alloc((size_t)B * M2 * 3), alloc((size_t)B * M2 * 3)};
  float* xyz3b[2] = {alloc((size_t)B * M3 * 3), alloc((size_t)B * M3 * 3)};
  float* S1bf[2] = {alloc((size_t)B * O1 * M1), alloc((size_t)B * O1 * M1)};
  float* S2bf[2] = {alloc((size_t)B * O2 * M2), alloc((size_t)B * O2 * M2)};
  float* S3bf[2] = {alloc((size_t)B * O3 * M3), alloc((size_t)B * O3 * M3)};
  float* feat2 = alloc((size_t)B * O1 * M2);
  float* feat3 = alloc((size_t)B * O2 * M3);
  float* l3 = alloc((size_t)B * 384 * M2);
  float* l2 = alloc((size_t)B * 448 * M1);
  float* iw = alloc((size_t)B * N0 * 3);
  int* ii = (int*)alloc((size_t)B * N0 * 3);
  int* idxc = (int*)alloc((size_t)B * M1 * NS1);
  int* idxq = (int*)alloc((size_t)B * M2 * NSQ);

  // zero-init the t=0 "previous state" buffers (ping index 1)
  hipMemsetAsync(xyz1b[1], 0, (size_t)B * M1 * 3 * 4, stream);
  hipMemsetAsync(xyz2b[1], 0, (size_t)B * M2 * 3 * 4, stream);
  hipMemsetAsync(xyz3b[1], 0, (size_t)B * M3 * 3 * 4, stream);
  hipMemsetAsync(S1bf[1], 0, (size_t)B * O1 * M1 * 4, stream);
  hipMemsetAsync(S2bf[1], 0, (size_t)B * O2 * M2 * 4, stream);
  hipMemsetAsync(S3bf[1], 0, (size_t)B * O3 * M3 * 4, stream);

  double r;
  r = 4.0 + 1e-6;         const float r2c1 = (float)(r * r);
  r = 2.0 * 4.0 / 4.0 + 1e-6; const float r2q2 = (float)(r * r);
  r = 2.0 * 4.0 + 1e-6;   const float r2c2 = (float)(r * r);
  r = 4.0 * 4.0 / 4.0 + 1e-6; const float r2q3 = (float)(r * r);
  r = 3.0 * 4.0 + 1e-6;   const float r2c3 = (float)(r * r);

  auto grid = [](int total) { return dim3((unsigned)((total + 255) / 256)); };

  int cur = 0;
  for (int t = 0; t < LF; ++t) {
    const bool enc = t < LF / 2;
    const float* W1 = enc ? enw[0] : dew[0];
    const float* W2 = enc ? enw[1] : dew[1];
    const float* W3 = enc ? enw[2] : dew[2];
    const float* fp;
    long fstr;
    if (enc) {
      fp = xyzs + (long)t * N0 * 3;
      fstr = (long)LF * N0 * 3;
    } else {
      if (t == LF / 2)
        copyframe_kernel<<<grid(B * N0 * 3), 256, 0, stream>>>(xyzs, frame, B * N0 * 3);
      fp = frame;
      fstr = (long)N0 * 3;
    }
    const int prev = 1 - cur;

    // ---- level 1 ----
    fps_fast<2048, 1024><<<B, 1024, 0, stream>>>(fp, fstr, M1, xyz1b[cur]);
    bq_kernel<<<grid(B * M1), 256, 0, stream>>>(xyz1b[cur], xyz1b[prev], r2c1, NS1, M1, M1,
                                                idxc, B * M1);
    cell_kernel<<<B * M1, O1, NS1 * C1 * 4, stream>>>(xyz1b[cur], nullptr, xyz1b[prev],
                                                      S1bf[prev], idxc, W1, S1bf[cur], M1,
                                                      NS1, 0, O1);
    // ---- level 2 ----
    fps_fast<1024, 1024><<<B, 1024, 0, stream>>>(xyz1b[cur], (long)M1 * 3, M2, xyz2b[cur]);
    bq_kernel<<<grid(B * M2), 256, 0, stream>>>(xyz2b[cur], xyz1b[cur], r2q2, NSQ, M2, M1,
                                                idxq, B * M2);
    gmax_kernel<<<grid(B * O1 * M2), 256, 0, stream>>>(S1bf[cur], idxq, feat2, O1, M2, M1,
                                                       NSQ, B * O1 * M2);
    bq_kernel<<<grid(B * M2), 256, 0, stream>>>(xyz2b[cur], xyz2b[prev], r2c2, NS2, M2, M2,
                                                idxc, B * M2);
    cell_kernel<<<B * M2, O2, NS2 * C2 * 4, stream>>>(xyz2b[cur], feat2, xyz2b[prev],
                                                      S2bf[prev], idxc, W2, S2bf[cur], M2,
                                                      NS2, O1, O2);
    // ---- level 3 ----
    fps_fast<512, 512><<<B, 512, 0, stream>>>(xyz2b[cur], (long)M2 * 3, M3, xyz3b[cur]);
    bq_kernel<<<grid(B * M3), 256, 0, stream>>>(xyz3b[cur], xyz2b[cur], r2q3, NSQ, M3, M2,
                                                idxq, B * M3);
    gmax_kernel<<<grid(B * O2 * M3), 256, 0, stream>>>(S2bf[cur], idxq, feat3, O2, M3, M2,
                                                       NSQ, B * O2 * M3);
    bq_kernel<<<grid(B * M3), 256, 0, stream>>>(xyz3b[cur], xyz3b[prev], r2c3, NS3, M3, M3,
                                                idxc, B * M3);
    cell_kernel<<<B * M3, O3, NS3 * C3 * 4, stream>>>(xyz3b[cur], feat3, xyz3b[prev],
                                                      S3bf[prev], idxc, W3, S3bf[cur], M3,
                                                      NS3, O2, O3);

    if (!enc) {
      const int td = t - LF / 2;
      // l3 = concat([interp(p2<-p3, f3), f2])
      knn3_kernel<<<grid(B * M2), 256, 0, stream>>>(xyz2b[cur], (long)M2 * 3, M2,
                                                    xyz3b[cur], M3, ii, iw, B * M2);
      interp_kernel<<<grid(B * O3 * M2), 256, 0, stream>>>(S3bf[cur], ii, iw, l3, O3, 0,
                                                           384, M3, M2, B * O3 * M2);
      copyrows_kernel<<<grid(B * O2 * M2), 256, 0, stream>>>(S2bf[cur], l3, O2, O3, 384,
                                                             M2, B * O2 * M2);
      // l2 = concat([interp(p1<-p2, l3), f1])
      knn3_kernel<<<grid(B * M1), 256, 0, stream>>>(xyz1b[cur], (long)M1 * 3, M1,
                                                    xyz2b[cur], M2, ii, iw, B * M1);
      interp_kernel<<<grid(B * 384 * M1), 256, 0, stream>>>(l3, ii, iw, l2, 384, 0, 448,
                                                            M2, M1, B * 384 * M1);
      copyrows_kernel<<<grid(B * O1 * M1), 256, 0, stream>>>(S1bf[cur], l2, O1, 384, 448,
                                                             M1, B * O1 * M1);
      // l1 = interp(frame<-p1, l2) fused into MLP; frame += motion; emit pred
      knn3_kernel<<<grid(B * N0), 256, 0, stream>>>(frame, (long)N0 * 3, N0, xyz1b[cur],
                                                    M1, ii, iw, B * N0);
      mlp_kernel<<<B * N0, 64, 0, stream>>>(l2, ii, iw, mw1, mb1, mw2, mb2, frame, out, td);
    }
    cur = prev;
  }
  (void)in_sizes; (void)n_in; (void)out_size; (void)ws_size;
}

// Round 3
// 15694.269 us; speedup vs baseline: 1.7557x; 1.3567x over previous
//
#include <hip/hip_runtime.h>

// ---------------- problem constants ----------------
static constexpr int B  = 4;
static constexpr int N0 = 2048;
static constexpr int LF = 8;
static constexpr int M1 = 1024, M2 = 512, M3 = 256;
static constexpr int O1 = 64, O2 = 128, O3 = 256;
static constexpr int NS1 = 12, NS2 = 8, NS3 = 4, NSQ = 4;
static constexpr int C1 = 67, C2 = 195, C3 = 387;

// Exact float32 squared distance in numpy's op order ((dx^2+dy^2)+dz^2),
// with _rn intrinsics to forbid FMA contraction (discrete decisions depend on it).
__device__ __forceinline__ float sq3(float ax, float ay, float az,
                                     float bx, float by, float bz) {
  float dx = __fsub_rn(ax, bx), dy = __fsub_rn(ay, by), dz = __fsub_rn(az, bz);
  return __fadd_rn(__fadd_rn(__fmul_rn(dx, dx), __fmul_rn(dy, dy)),
                   __fmul_rn(dz, dz));
}

// u64-key (hi=dist bits, lo=0x7FFFFFFF-idx) max combine with DPP neighbor fetch.
// VALU pipe only — no LDS traffic. Self-fallback (bound_ctrl=false, old=self)
// is harmless because max is idempotent.
template <int CTRL>
__device__ __forceinline__ void dpp_max_step(unsigned& hi, unsigned& lo) {
  unsigned ohi = (unsigned)__builtin_amdgcn_update_dpp((int)hi, (int)hi, CTRL, 0xf, 0xf, false);
  unsigned olo = (unsigned)__builtin_amdgcn_update_dpp((int)lo, (int)lo, CTRL, 0xf, 0xf, false);
  bool take = (ohi > hi) || (ohi == hi && olo > lo);
  hi = take ? ohi : hi;
  lo = take ? olo : lo;
}

// ---------------- furthest point sampling (DPP reduction) ----------------
// One block (256 thr = 4 waves, 1/SIMD) per batch. Thread t owns points
// t*K..t*K+K-1 with dist in registers. Per iteration: register dist update,
// DPP wave argmax (row_shr 1/2/4/8 + row_bcast15/31 -> lane 63), readlane,
// one LDS uint2 per wave, ONE parity-double-buffered barrier, 4-way scalar
// combine, broadcast coord read. Tie-break = first occurrence (min idx),
// matching jnp.argmax, via lo = 0x7FFFFFFF - idx.
template <int N>
__global__ __launch_bounds__(256) void fps_dpp(const float* __restrict__ pts,
                                               long bstride, int npoint,
                                               float* __restrict__ out) {
  constexpr int K = N / 256;
  const int b = blockIdx.x;
  const float* p = pts + (long)b * bstride;
  const int tid = threadIdx.x;
  const int lane = tid & 63;
  const int wid = tid >> 6;
  __shared__ float spx[N], spy[N], spz[N];
  __shared__ uint2 wbest[2][4];
  float ppx[K], ppy[K], ppz[K], dist[K];
#pragma unroll
  for (int k = 0; k < K; ++k) {
    const int j = tid * K + k;
    const float x = p[3 * j], y = p[3 * j + 1], z = p[3 * j + 2];
    ppx[k] = x; ppy[k] = y; ppz[k] = z;
    spx[j] = x; spy[j] = y; spz[j] = z;
    dist[k] = 1e10f;
  }
  __syncthreads();
  float lx = spx[0], ly = spy[0], lz = spz[0];
  float* outb = out + (long)b * npoint * 3;
  const unsigned base = 0x7FFFFFFFu - (unsigned)(tid * K);
  for (int i = 0; i < npoint; ++i) {
    if (tid == 0) {
      outb[3 * i + 0] = lx; outb[3 * i + 1] = ly; outb[3 * i + 2] = lz;
    }
    unsigned bhi = 0u, blo = 0u;
#pragma unroll
    for (int k = 0; k < K; ++k) {
      const float d = sq3(ppx[k], ppy[k], ppz[k], lx, ly, lz);
      const float dm = fminf(dist[k], d);
      dist[k] = dm;
      const unsigned h = __float_as_uint(dm);
      const unsigned l = base - (unsigned)k;
      const bool take = (h > bhi) || (h == bhi && l > blo);
      bhi = take ? h : bhi;
      blo = take ? l : blo;
    }
    // wave64 max-reduce on VALU pipe; result lands in lane 63
    dpp_max_step<0x111>(bhi, blo);  // row_shr:1
    dpp_max_step<0x112>(bhi, blo);  // row_shr:2
    dpp_max_step<0x114>(bhi, blo);  // row_shr:4
    dpp_max_step<0x118>(bhi, blo);  // row_shr:8
    dpp_max_step<0x142>(bhi, blo);  // row_bcast15
    dpp_max_step<0x143>(bhi, blo);  // row_bcast31
    const unsigned whi = (unsigned)__builtin_amdgcn_readlane((int)bhi, 63);
    const unsigned wlo = (unsigned)__builtin_amdgcn_readlane((int)blo, 63);
    if (lane == 0) wbest[i & 1][wid] = make_uint2(whi, wlo);
    __syncthreads();
    unsigned long long gk = 0ull;
#pragma unroll
    for (int w = 0; w < 4; ++w) {
      const uint2 e = wbest[i & 1][w];
      const unsigned long long k64 = ((unsigned long long)e.x << 32) | e.y;
      gk = (k64 > gk) ? k64 : gk;
    }
    const int gidx = 0x7FFFFFFF - (int)(gk & 0xFFFFFFFFu);
    lx = spx[gidx]; ly = spy[gidx]; lz = spz[gidx];
  }
}

// ---------------- ball query ----------------
// First ns in-range indices in ascending order; pad with first; 0 if none.
__global__ __launch_bounds__(256) void bq_kernel(const float* __restrict__ nxyz,
                                                 const float* __restrict__ sxyz,
                                                 float r2, int ns, int M, int Ns,
                                                 int* __restrict__ idx, int total) {
  int t = blockIdx.x * 256 + threadIdx.x;
  if (t >= total) return;
  int b = t / M;
  const float* q = nxyz + (long)t * 3;
  const float qx = q[0], qy = q[1], qz = q[2];
  const float* s = sxyz + (long)b * Ns * 3;
  int* o = idx + (long)t * ns;
  int cnt = 0;
  for (int j = 0; j < Ns; ++j) {
    float d2 = sq3(qx, qy, qz, s[3 * j], s[3 * j + 1], s[3 * j + 2]);
    if (d2 < r2) {
      o[cnt++] = j;
      if (cnt == ns) break;
    }
  }
  int fill = (cnt > 0) ? o[0] : 0;
  for (int k = cnt; k < ns; ++k) o[k] = fill;
}

// ---------------- point-rnn cell: S_out = max_s W @ [S2g; X1; disp] ----------------
// One block per (b,m), blockDim == O (one thread per output channel).
__global__ void cell_kernel(const float* __restrict__ P1, const float* __restrict__ X1,
                            const float* __restrict__ P2, const float* __restrict__ S2,
                            const int* __restrict__ idx, const float* __restrict__ W,
                            float* __restrict__ Sout, int M, int ns, int Cin, int O) {
  const int C = O + Cin + 3;
  const int bm = blockIdx.x;
  const int b = bm / M, m = bm - b * M;
  extern __shared__ float corr[];  // ns*C
  const int* id = idx + (long)bm * ns;
  const float p1x = P1[bm * 3 + 0], p1y = P1[bm * 3 + 1], p1z = P1[bm * 3 + 2];
  for (int e = threadIdx.x; e < ns * C; e += blockDim.x) {
    int s = e / C, c = e - s * C;
    int j = id[s];
    float v;
    if (c < O) {
      v = S2[((long)b * O + c) * M + j];
    } else if (c < O + Cin) {
      v = X1[((long)b * Cin + (c - O)) * M + m];
    } else {
      int d = c - O - Cin;
      float pj = P2[((long)b * M + j) * 3 + d];
      float pm = (d == 0) ? p1x : ((d == 1) ? p1y : p1z);
      v = __fsub_rn(pj, pm);
    }
    corr[e] = v;
  }
  __syncthreads();
  const int o = threadIdx.x;
  const float* w = W + (long)o * C;
  float best = -3.0e38f;
  for (int s = 0; s < ns; ++s) {
    const float* cs = corr + s * C;
    float acc = 0.f;
    for (int c = 0; c < C; ++c) acc = fmaf(w[c], cs[c], acc);
    best = fmaxf(best, acc);
  }
  Sout[((long)b * O + o) * M + m] = best;
}

// ---------------- grouped feature max ----------------
__global__ __launch_bounds__(256) void gmax_kernel(const float* __restrict__ feat,
                                                   const int* __restrict__ idx,
                                                   float* __restrict__ out, int Cc,
                                                   int M, int Ms, int ns, int total) {
  int t = blockIdx.x * 256 + threadIdx.x;
  if (t >= total) return;
  int m = t % M;
  int bc = t / M;
  int b = bc / Cc;
  const int* id = idx + ((long)b * M + m) * ns;
  const float* f = feat + (long)bc * Ms;
  float best = -3.0e38f;
  for (int s = 0; s < ns; ++s) best = fmaxf(best, f[id[s]]);
  out[t] = best;
}

// ---------------- 3-NN + inverse-distance weights ----------------
// Strict '<' insertion matches lax.top_k tie semantics (lower index first).
__global__ __launch_bounds__(256) void knn3_kernel(const float* __restrict__ unk,
                                                   long ubstride, int Mu,
                                                   const float* __restrict__ kn, int Mk,
                                                   int* __restrict__ oi,
                                                   float* __restrict__ ow, int total) {
  int t = blockIdx.x * 256 + threadIdx.x;
  if (t >= total) return;
  int b = t / Mu, m = t - b * Mu;
  const float* q = unk + (long)b * ubstride + (long)m * 3;
  const float qx = q[0], qy = q[1], qz = q[2];
  const float* s = kn + (long)b * Mk * 3;
  float d0 = 3e38f, d1 = 3e38f, d2v = 3e38f;
  int i0 = 0, i1 = 0, i2 = 0;
  for (int j = 0; j < Mk; ++j) {
    float dd = sq3(qx, qy, qz, s[3 * j], s[3 * j + 1], s[3 * j + 2]);
    if (dd < d0) {
      d2v = d1; i2 = i1; d1 = d0; i1 = i0; d0 = dd; i0 = j;
    } else if (dd < d1) {
      d2v = d1; i2 = i1; d1 = dd; i1 = j;
    } else if (dd < d2v) {
      d2v = dd; i2 = j;
    }
  }
  float r0 = 1.0f / __fadd_rn(d0, 1e-8f);
  float r1 = 1.0f / __fadd_rn(d1, 1e-8f);
  float r2 = 1.0f / __fadd_rn(d2v, 1e-8f);
  float sum = __fadd_rn(__fadd_rn(r0, r1), r2);
  ow[t * 3 + 0] = r0 / sum;
  ow[t * 3 + 1] = r1 / sum;
  ow[t * 3 + 2] = r2 / sum;
  oi[t * 3 + 0] = i0;
  oi[t * 3 + 1] = i1;
  oi[t * 3 + 2] = i2;
}

// ---------------- weighted 3-gather (interp) into concat region ----------------
__global__ __launch_bounds__(256) void interp_kernel(const float* __restrict__ f,
                                                     const int* __restrict__ ii,
                                                     const float* __restrict__ iw,
                                                     float* __restrict__ out, int Cc,
                                                     int Coff, int Ctot, int Ms, int Md,
                                                     int total) {
  int t = blockIdx.x * 256 + threadIdx.x;
  if (t >= total) return;
  int m = t % Md;
  int bc = t / Md;
  int c = bc % Cc;
  int b = bc / Cc;
  const int* id = ii + ((long)b * Md + m) * 3;
  const float* w = iw + ((long)b * Md + m) * 3;
  const float* fb = f + ((long)b * Cc + c) * Ms;
  float v = __fadd_rn(__fadd_rn(__fmul_rn(fb[id[0]], w[0]), __fmul_rn(fb[id[1]], w[1])),
                      __fmul_rn(fb[id[2]], w[2]));
  out[((long)b * Ctot + Coff + c) * Md + m] = v;
}

__global__ __launch_bounds__(256) void copyrows_kernel(const float* __restrict__ f,
                                                       float* __restrict__ out, int Cc,
                                                       int Coff, int Ctot, int M,
                                                       int total) {
  int t = blockIdx.x * 256 + threadIdx.x;
  if (t >= total) return;
  int m = t % M;
  int bc = t / M;
  int c = bc % Cc;
  int b = bc / Cc;
  out[((long)b * Ctot + Coff + c) * M + m] = f[t];
}

__global__ __launch_bounds__(256) void copyframe_kernel(const float* __restrict__ xyzs,
                                                        float* __restrict__ frame,
                                                        int total) {
  int t = blockIdx.x * 256 + threadIdx.x;
  if (t >= total) return;
  int b = t / (N0 * 3);
  int rr = t - b * (N0 * 3);
  frame[t] = xyzs[((long)b * LF + (LF / 2 - 1)) * (N0 * 3) + rr];
}

// ---------------- fused interp-to-l1 + 2-layer MLP + frame update ----------------
__global__ __launch_bounds__(64) void mlp_kernel(const float* __restrict__ l2,
                                                 const int* __restrict__ ii,
                                                 const float* __restrict__ iw,
                                                 const float* __restrict__ W1,
                                                 const float* __restrict__ b1,
                                                 const float* __restrict__ W2,
                                                 const float* __restrict__ b2,
                                                 float* __restrict__ frame,
                                                 float* __restrict__ out, int td) {
  const int bn = blockIdx.x;
  const int b = bn / N0, n = bn - b * N0;
  __shared__ float col[448];
  __shared__ float h[64];
  const int* id = ii + (long)bn * 3;
  const float* w = iw + (long)bn * 3;
  const float w0 = w[0], w1 = w[1], w2v = w[2];
  const int i0 = id[0], i1 = id[1], i2 = id[2];
  const float* l2b = l2 + (long)b * 448 * M1;
  for (int c = threadIdx.x; c < 448; c += 64) {
    const float* r = l2b + (long)c * M1;
    col[c] = __fadd_rn(__fadd_rn(__fmul_rn(r[i0], w0), __fmul_rn(r[i1], w1)),
                       __fmul_rn(r[i2], w2v));
  }
  __syncthreads();
  const int o = threadIdx.x;
  const float* wr = W1 + (long)o * 448;
  float acc = b1[o];
  for (int c = 0; c < 448; ++c) acc = fmaf(wr[c], col[c], acc);
  h[o] = fmaxf(acc, 0.0f);
  __syncthreads();
  if (o < 3) {
    const float* w2r = W2 + o * 64;
    float acc2 = b2[o];
    for (int c = 0; c < 64; ++c) acc2 = fmaf(w2r[c], h[c], acc2);
    float nf = frame[(long)bn * 3 + o] + acc2;
    frame[(long)bn * 3 + o] = nf;
    out[(((long)b * 4 + td) * N0 + n) * 3 + o] = nf;
  }
}

extern "C" void kernel_launch(void* const* d_in, const int* in_sizes, int n_in,
                              void* d_out, int out_size, void* d_ws, size_t ws_size,
                              hipStream_t stream) {
  const float* xyzs = (const float*)d_in[0];
  const float* enw[3] = {(const float*)d_in[1], (const float*)d_in[2], (const float*)d_in[3]};
  const float* dew[3] = {(const float*)d_in[4], (const float*)d_in[5], (const float*)d_in[6]};
  const float* mw1 = (const float*)d_in[7];
  const float* mb1 = (const float*)d_in[8];
  const float* mw2 = (const float*)d_in[9];
  const float* mb2 = (const float*)d_in[10];
  float* out = (float*)d_out;

  float* ws = (float*)d_ws;
  size_t off = 0;
  auto alloc = [&](size_t nn) { float* p = ws + off; off += nn; return p; };
  float* frame = alloc((size_t)B * N0 * 3);
  float* xyz1b[2] = {alloc((size_t)B * M1 * 3), alloc((size_t)B * M1 * 3)};
  float* xyz2b[2] = {alloc((size_t)B * M2 * 3), alloc((size_t)B * M2 * 3)};
  float* xyz3b[2] = {alloc((size_t)B * M3 * 3), alloc((size_t)B * M3 * 3)};
  float* S1bf[2] = {alloc((size_t)B * O1 * M1), alloc((size_t)B * O1 * M1)};
  float* S2bf[2] = {alloc((size_t)B * O2 * M2), alloc((size_t)B * O2 * M2)};
  float* S3bf[2] = {alloc((size_t)B * O3 * M3), alloc((size_t)B * O3 * M3)};
  float* feat2 = alloc((size_t)B * O1 * M2);
  float* feat3 = alloc((size_t)B * O2 * M3);
  float* l3 = alloc((size_t)B * 384 * M2);
  float* l2 = alloc((size_t)B * 448 * M1);
  float* iw = alloc((size_t)B * N0 * 3);
  int* ii = (int*)alloc((size_t)B * N0 * 3);
  int* idxc = (int*)alloc((size_t)B * M1 * NS1);
  int* idxq = (int*)alloc((size_t)B * M2 * NSQ);

  // zero-init the t=0 "previous state" buffers (ping index 1)
  hipMemsetAsync(xyz1b[1], 0, (size_t)B * M1 * 3 * 4, stream);
  hipMemsetAsync(xyz2b[1], 0, (size_t)B * M2 * 3 * 4, stream);
  hipMemsetAsync(xyz3b[1], 0, (size_t)B * M3 * 3 * 4, stream);
  hipMemsetAsync(S1bf[1], 0, (size_t)B * O1 * M1 * 4, stream);
  hipMemsetAsync(S2bf[1], 0, (size_t)B * O2 * M2 * 4, stream);
  hipMemsetAsync(S3bf[1], 0, (size_t)B * O3 * M3 * 4, stream);

  double r;
  r = 4.0 + 1e-6;         const float r2c1 = (float)(r * r);
  r = 2.0 * 4.0 / 4.0 + 1e-6; const float r2q2 = (float)(r * r);
  r = 2.0 * 4.0 + 1e-6;   const float r2c2 = (float)(r * r);
  r = 4.0 * 4.0 / 4.0 + 1e-6; const float r2q3 = (float)(r * r);
  r = 3.0 * 4.0 + 1e-6;   const float r2c3 = (float)(r * r);

  auto grid = [](int total) { return dim3((unsigned)((total + 255) / 256)); };

  int cur = 0;
  for (int t = 0; t < LF; ++t) {
    const bool enc = t < LF / 2;
    const float* W1 = enc ? enw[0] : dew[0];
    const float* W2 = enc ? enw[1] : dew[1];
    const float* W3 = enc ? enw[2] : dew[2];
    const float* fp;
    long fstr;
    if (enc) {
      fp = xyzs + (long)t * N0 * 3;
      fstr = (long)LF * N0 * 3;
    } else {
      if (t == LF / 2)
        copyframe_kernel<<<grid(B * N0 * 3), 256, 0, stream>>>(xyzs, frame, B * N0 * 3);
      fp = frame;
      fstr = (long)N0 * 3;
    }
    const int prev = 1 - cur;

    // ---- level 1 ----
    fps_dpp<2048><<<B, 256, 0, stream>>>(fp, fstr, M1, xyz1b[cur]);
    bq_kernel<<<grid(B * M1), 256, 0, stream>>>(xyz1b[cur], xyz1b[prev], r2c1, NS1, M1, M1,
                                                idxc, B * M1);
    cell_kernel<<<B * M1, O1, NS1 * C1 * 4, stream>>>(xyz1b[cur], nullptr, xyz1b[prev],
                                                      S1bf[prev], idxc, W1, S1bf[cur], M1,
                                                      NS1, 0, O1);
    // ---- level 2 ----
    fps_dpp<1024><<<B, 256, 0, stream>>>(xyz1b[cur], (long)M1 * 3, M2, xyz2b[cur]);
    bq_kernel<<<grid(B * M2), 256, 0, stream>>>(xyz2b[cur], xyz1b[cur], r2q2, NSQ, M2, M1,
                                                idxq, B * M2);
    gmax_kernel<<<grid(B * O1 * M2), 256, 0, stream>>>(S1bf[cur], idxq, feat2, O1, M2, M1,
                                                       NSQ, B * O1 * M2);
    bq_kernel<<<grid(B * M2), 256, 0, stream>>>(xyz2b[cur], xyz2b[prev], r2c2, NS2, M2, M2,
                                                idxc, B * M2);
    cell_kernel<<<B * M2, O2, NS2 * C2 * 4, stream>>>(xyz2b[cur], feat2, xyz2b[prev],
                                                      S2bf[prev], idxc, W2, S2bf[cur], M2,
                                                      NS2, O1, O2);
    // ---- level 3 ----
    fps_dpp<512><<<B, 256, 0, stream>>>(xyz2b[cur], (long)M2 * 3, M3, xyz3b[cur]);
    bq_kernel<<<grid(B * M3), 256, 0, stream>>>(xyz3b[cur], xyz2b[cur], r2q3, NSQ, M3, M2,
                                                idxq, B * M3);
    gmax_kernel<<<grid(B * O2 * M3), 256, 0, stream>>>(S2bf[cur], idxq, feat3, O2, M3, M2,
                                                       NSQ, B * O2 * M3);
    bq_kernel<<<grid(B * M3), 256, 0, stream>>>(xyz3b[cur], xyz3b[prev], r2c3, NS3, M3, M3,
                                                idxc, B * M3);
    cell_kernel<<<B * M3, O3, NS3 * C3 * 4, stream>>>(xyz3b[cur], feat3, xyz3b[prev],
                                                      S3bf[prev], idxc, W3, S3bf[cur], M3,
                                                      NS3, O2, O3);

    if (!enc) {
      const int td = t - LF / 2;
      // l3 = concat([interp(p2<-p3, f3), f2])
      knn3_kernel<<<grid(B * M2), 256, 0, stream>>>(xyz2b[cur], (long)M2 * 3, M2,
                                                    xyz3b[cur], M3, ii, iw, B * M2);
      interp_kernel<<<grid(B * O3 * M2), 256, 0, stream>>>(S3bf[cur], ii, iw, l3, O3, 0,
                                                           384, M3, M2, B * O3 * M2);
      copyrows_kernel<<<grid(B * O2 * M2), 256, 0, stream>>>(S2bf[cur], l3, O2, O3, 384,
                                                             M2, B * O2 * M2);
      // l2 = concat([interp(p1<-p2, l3), f1])
      knn3_kernel<<<grid(B * M1), 256, 0, stream>>>(xyz1b[cur], (long)M1 * 3, M1,
                                                    xyz2b[cur], M2, ii, iw, B * M1);
      interp_kernel<<<grid(B * 384 * M1), 256, 0, stream>>>(l3, ii, iw, l2, 384, 0, 448,
                                                            M2, M1, B * 384 * M1);
      copyrows_kernel<<<grid(B * O1 * M1), 256, 0, stream>>>(S1bf[cur], l2, O1, 384, 448,
                                                             M1, B * O1 * M1);
      // l1 = interp(frame<-p1, l2) fused into MLP; frame += motion; emit pred
      knn3_kernel<<<grid(B * N0), 256, 0, stream>>>(frame, (long)N0 * 3, N0, xyz1b[cur],
                                                    M1, ii, iw, B * N0);
      mlp_kernel<<<B * N0, 64, 0, stream>>>(l2, ii, iw, mw1, mb1, mw2, mb2, frame, out, td);
    }
    cur = prev;
  }
  (void)in_sizes; (void)n_in; (void)out_size; (void)ws_size;
}